// Round 16
// baseline (1195.607 us; speedup 1.0000x reference)
//
#include <hip/hip_runtime.h>
#include <hip/hip_bf16.h>

// Problem constants (from reference)
constexpr int BB = 16;     // batches
constexpr int NN = 8192;   // points
constexpr int SS = 1024;   // samples (FPS)
constexpr int KK = 32;     // kNN
constexpr int BUFC = 256;  // per-wave candidate buffer (keys <= That)

typedef float f2 __attribute__((ext_vector_type(2)));

__device__ __forceinline__ float b2f(__hip_bfloat16 h) { return __bfloat162float(h); }

// Monotone map f32 -> u32 (order-preserving, bijective; d is never -0 here).
__device__ __forceinline__ unsigned mkey32(float d) {
    unsigned u = __float_as_uint(d);
    return u ^ (0x80000000u | (unsigned)((int)u >> 31));
}

// Deterministic distance key for point idx vs query (qx,qy,qz,qq).
// Same expression sequence every call -> bit-identical results (IEEE, no FMA).
__device__ __forceinline__ unsigned long long dist_key(const float* __restrict__ pb,
                                                       int idx, float qx, float qy,
                                                       float qz, float qq) {
    float px = pb[idx * 3 + 0];
    float py = pb[idx * 3 + 1];
    float pz = pb[idx * 3 + 2];
    float dot = __fadd_rn(__fadd_rn(__fmul_rn(qx, px), __fmul_rn(qy, py)), __fmul_rn(qz, pz));
    float pp  = __fadd_rn(__fadd_rn(__fmul_rn(px, px), __fmul_rn(py, py)), __fmul_rn(pz, pz));
    float d = __fadd_rn(__fadd_rn(__fmul_rn(-2.0f, dot), qq), pp);
    return ((unsigned long long)mkey32(d) << 32) | (unsigned)idx;
}

// DPP lane-move of a u64 (both halves move identically).
template <int CTRL, int RMASK>
__device__ __forceinline__ unsigned long long dppmove_u64(unsigned long long v) {
    int lo = (int)(unsigned)v, hi = (int)(unsigned)(v >> 32);
    int nlo = __builtin_amdgcn_update_dpp(lo, lo, CTRL, RMASK, 0xf, false);
    int nhi = __builtin_amdgcn_update_dpp(hi, hi, CTRL, RMASK, 0xf, false);
    return ((unsigned long long)(unsigned)nhi << 32) | (unsigned)nlo;
}

__device__ __forceinline__ unsigned long long u64max(unsigned long long a,
                                                     unsigned long long b) {
    return a > b ? a : b;
}

// Wave64 max-reduce via DPP. Lane 63 holds the max.
__device__ __forceinline__ unsigned long long wave_max_dpp(unsigned long long k) {
    k = u64max(k, dppmove_u64<0x121, 0xf>(k));  // row_ror:1
    k = u64max(k, dppmove_u64<0x122, 0xf>(k));  // row_ror:2
    k = u64max(k, dppmove_u64<0x124, 0xf>(k));  // row_ror:4
    k = u64max(k, dppmove_u64<0x128, 0xf>(k));  // row_ror:8
    k = u64max(k, dppmove_u64<0x142, 0xa>(k));  // row_bcast:15 -> rows 1,3
    k = u64max(k, dppmove_u64<0x143, 0xc>(k));  // row_bcast:31 -> rows 2,3
    return k;
}

// Cross-lane bitonic sort of 64 u64 keys (ascending); lane i ends with i-th smallest.
__device__ __forceinline__ unsigned long long bitonic64(unsigned long long v, int lane) {
#pragma unroll
    for (int k = 2; k <= 64; k <<= 1) {
#pragma unroll
        for (int j = k >> 1; j > 0; j >>= 1) {
            unsigned long long p = __shfl_xor(v, j);
            bool up = ((lane & k) == 0);
            bool lower = ((lane & j) == 0);
            bool take_min = (up == lower);
            v = take_min ? (p < v ? p : v) : (p > v ? p : v);
        }
    }
    return v;
}

// ---------------------------------------------------------------------------
// K0: dtype detection + params upcast + sentinel fill of d_out.
// (xyzf conversion moved into fps_kernel — r16: kills a 512-block kernel.)
// ---------------------------------------------------------------------------
__global__ __launch_bounds__(256) void convert_kernel(
    const void* __restrict__ xyz_raw, const void* __restrict__ g1r,
    const void* __restrict__ b1r, const void* __restrict__ g2r,
    const void* __restrict__ b2r, float* __restrict__ params,
    void* __restrict__ out_raw) {
    const unsigned short* u = (const unsigned short*)xyz_raw;
    unsigned short s = u[2 * (threadIdx.x & 63)];
    int e = (s >> 7) & 0xFF;
    unsigned long long m = __ballot(e >= 100 && e <= 140);
    bool isbf = __popcll(m) > 48;

    if (blockIdx.x == 0 && threadIdx.x < 85) {
        int t = threadIdx.x;
        if (t == 84) {
            params[84] = isbf ? 1.0f : 0.0f;
        } else {
            const void* src; int off;
            if (t < 6)       { src = g1r; off = t; }
            else if (t < 12) { src = b1r; off = t - 6; }
            else if (t < 48) { src = g2r; off = t - 12; }
            else             { src = b2r; off = t - 48; }
            params[t] = isbf ? b2f(((const __hip_bfloat16*)src)[off])
                             : ((const float*)src)[off];
        }
    }
    if (blockIdx.x == 1 && threadIdx.x < 64) {
        for (int i = threadIdx.x; i < 576; i += 64) {
            if (isbf) ((__hip_bfloat16*)out_raw)[i] = __float2bfloat16(1.0f);
            else      ((float*)out_raw)[i] = 1.0f;
        }
    }
}

// ---------------------------------------------------------------------------
// K1: Farthest point sampling — r7 structure + r16 changes:
//  (a) converts its own batch from raw input (flag in params[84]) and writes
//      xyzf (for knn) + sxyz (LDS) in one pass — removes the big convert pass;
//  (b) distance chain in PACKED f32 (ext_vector_type(2), plain operators
//      under `#pragma clang fp contract(off)`): LLVM selects v_pk_add/mul_f32
//      on gfx950 (2x f32 issue). contract(off) blocks FMA fusion, so every
//      element op is the same IEEE RNE add/mul as __fadd_rn/__fmul_rn —
//      BIT-EXACT either way; if ISel declines to pack it degenerates to
//      exactly the old scalar code (free bet).
// Tie-break preserved: flat j ascending (pairs (2k,2k+1) tested .x then .y),
// strictly-greater keeps first -> lowest idx, identical to rounds 4-15.
// amdgpu_waves_per_eu(2,2): 256-VGPR budget, arrays stay in arch VGPRs.
// r8/r9: multi-CU fps loses (handshake ~1.4 us/step). r14: fusing knn under
// fps stretches fps 948->1300. Both abandoned on measurement.
// ---------------------------------------------------------------------------
__global__ __attribute__((amdgpu_flat_work_group_size(512, 512)))
__attribute__((amdgpu_waves_per_eu(2, 2)))
void fps_kernel(const void* __restrict__ xyz_raw, float* __restrict__ xyzf,
                float* __restrict__ new_xyz, const float* __restrict__ params) {
    constexpr int T = 512, P = NN / T;  // 16 points per thread, idx = t + j*T
    const int b = blockIdx.x, t = threadIdx.x;

    __shared__ float sxyz[NN * 3];          // 96 KB coord table
    __shared__ unsigned long long skey[2][8];

    // ---- convert this batch: raw -> xyzf (global, for knn) + sxyz (LDS) ----
    bool isbf = params[84] != 0.0f;
    float* xbo = xyzf + (size_t)b * NN * 3;
    if (isbf) {
        const __hip_bfloat16* r = (const __hip_bfloat16*)xyz_raw + (size_t)b * NN * 3;
        for (int i = t; i < NN * 3; i += T) {
            float v = b2f(r[i]);
            xbo[i] = v; sxyz[i] = v;
        }
    } else {
        const float* r = (const float*)xyz_raw + (size_t)b * NN * 3;
        for (int i = t; i < NN * 3; i += T) {
            float v = r[i];
            xbo[i] = v; sxyz[i] = v;
        }
    }
    __syncthreads();   // sxyz complete

    // ---- register state: 8 packed pairs per coord; pair k = points (2k,2k+1)
    f2 px2[P / 2], py2[P / 2], pz2[P / 2];
    float ds[P];
#pragma unroll
    for (int k = 0; k < P / 2; k++) {
        int p0 = t + (2 * k) * T, p1 = t + (2 * k + 1) * T;
        px2[k] = (f2){sxyz[p0 * 3 + 0], sxyz[p1 * 3 + 0]};
        py2[k] = (f2){sxyz[p0 * 3 + 1], sxyz[p1 * 3 + 1]};
        pz2[k] = (f2){sxyz[p0 * 3 + 2], sxyz[p1 * 3 + 2]};
        ds[2 * k] = 1e10f; ds[2 * k + 1] = 1e10f;
    }

    float cx = sxyz[0], cy = sxyz[1], cz = sxyz[2];
    if (t == 0) {
        float* o = new_xyz + (size_t)b * SS * 3;
        o[0] = cx; o[1] = cy; o[2] = cz;
    }
    const int wave = t >> 6, lane = t & 63;

    for (int step = 1; step < SS; step++) {
#pragma clang fp contract(off)
        f2 c2x = {cx, cx}, c2y = {cy, cy}, c2z = {cz, cz};
        float bv = -1.0f; int bj = 0;
#pragma unroll
        for (int k = 0; k < P / 2; k++) {
            f2 dx = px2[k] - c2x;                    // packed IEEE sub
            f2 dy = py2[k] - c2y;
            f2 dz = pz2[k] - c2z;
            f2 d2 = (dx * dx + dy * dy) + dz * dz;   // same association as scalar
            float m0 = fminf(ds[2 * k], d2.x);
            ds[2 * k] = m0;
            if (m0 > bv) { bv = m0; bj = 2 * k; }        // ascending flat j
            float m1 = fminf(ds[2 * k + 1], d2.y);
            ds[2 * k + 1] = m1;
            if (m1 > bv) { bv = m1; bj = 2 * k + 1; }
        }
        unsigned idx = (unsigned)(t + bj * T);
        unsigned long long key =
            ((unsigned long long)__float_as_uint(bv) << 32) | (unsigned)(~idx);

        key = wave_max_dpp(key);
        const int par = step & 1;
        if (lane == 63) skey[par][wave] = key;
        __syncthreads();

        unsigned long long k0 = u64max(skey[par][0], skey[par][1]);
        unsigned long long k1 = u64max(skey[par][2], skey[par][3]);
        unsigned long long k2 = u64max(skey[par][4], skey[par][5]);
        unsigned long long k3 = u64max(skey[par][6], skey[par][7]);
        unsigned long long bk = u64max(u64max(k0, k1), u64max(k2, k3));

        unsigned gidx = ~(unsigned)bk;      // winner point index (global in batch)
        cx = sxyz[gidx * 3 + 0];            // LDS broadcast (same bits as global)
        cy = sxyz[gidx * 3 + 1];
        cz = sxyz[gidx * 3 + 2];
        if (t == 0) {
            float* o = new_xyz + ((size_t)b * SS + step) * 3;
            o[0] = cx; o[1] = cy; o[2] = cz;
        }
    }
}

// ---------------------------------------------------------------------------
// K2 (RECOMPUTE): kNN via exact threshold selection, one wave per query,
// NO per-lane key array (r13/r14: mk[128] spilled to scratch -> 2.2 GB HBM).
// Pass 1 tracks only the lane-min key; pass 2 recomputes each key for the
// compaction test. IEEE ops on immutable inputs -> bit-identical keys.
// ---------------------------------------------------------------------------
__global__ __launch_bounds__(256, 2) void knn_kernel(const float* __restrict__ xyzf,
                                                     const float* __restrict__ new_xyz,
                                                     float* __restrict__ A,
                                                     double* __restrict__ qstats) {
    __shared__ unsigned long long buf[4][BUFC];
    const int t = threadIdx.x;
    const int lane = t & 63, wv = t >> 6;
    const int w = blockIdx.x * 4 + wv;          // global wave id = query id
    const int b = w >> 10, s = w & 1023;

    const float* q = new_xyz + ((size_t)b * SS + s) * 3;
    float qx = q[0], qy = q[1], qz = q[2];
    float qq = __fadd_rn(__fadd_rn(__fmul_rn(qx, qx), __fmul_rn(qy, qy)), __fmul_rn(qz, qz));

    const float* pb = xyzf + (size_t)b * NN * 3;
    const unsigned long long ltmask = (1ull << lane) - 1ull;

    // pass 1: lane-min key only (no storage)
    unsigned long long lmin = ~0ull;
    for (int j = 0; j < 128; j++) {
        unsigned long long key = dist_key(pb, j * 64 + lane, qx, qy, qz, qq);
        lmin = key < lmin ? key : lmin;
    }

    unsigned long long vs = bitonic64(lmin, lane);
    unsigned long long That = __shfl(vs, 31);

    // pass 2: recompute keys, compact keys <= That into LDS
    for (int i = lane; i < BUFC; i += 64) buf[wv][i] = ~0ull;
    int base = 0;
    for (int j = 0; j < 128; j++) {
        unsigned long long key = dist_key(pb, j * 64 + lane, qx, qy, qz, qq);
        bool f = key <= That;
        unsigned long long bal = __ballot(f);
        int pos = base + __popcll(bal & ltmask);
        if (f && pos < BUFC) buf[wv][pos] = key;
        base += __popcll(bal);
    }

    // rare recovery: tighten threshold (recompute inside search)
    if (base > BUFC) {
        unsigned lo = 0, hi = (unsigned)(That >> 32);
        for (int it = 0; it < 32; it++) {
            unsigned mid = lo + ((hi - lo) >> 1);
            int c = 0;
            for (int j = 0; j < 128; j++) {
                unsigned long long key = dist_key(pb, j * 64 + lane, qx, qy, qz, qq);
                c += ((unsigned)(key >> 32) <= mid) ? 1 : 0;
            }
#pragma unroll
            for (int o = 32; o > 0; o >>= 1) c += __shfl_xor(c, o);
            if (c >= 32) hi = mid; else lo = mid + 1;
        }
        That = ((unsigned long long)hi << 32) | 0xFFFFFFFFull;
        for (int i = lane; i < BUFC; i += 64) buf[wv][i] = ~0ull;
        base = 0;
        for (int j = 0; j < 128; j++) {
            unsigned long long key = dist_key(pb, j * 64 + lane, qx, qy, qz, qq);
            bool f = key <= That;
            unsigned long long bal = __ballot(f);
            int pos = base + __popcll(bal & ltmask);
            if (f && pos < BUFC) buf[wv][pos] = key;
            base += __popcll(bal);
        }
        if (base > BUFC) base = BUFC;
    }

    int M = base;
    unsigned long long kept = ~0ull;
    if (M <= 64) {
        unsigned long long v = (lane < M) ? buf[wv][lane] : ~0ull;
        v = bitonic64(v, lane);
        kept = v;
    } else {
        unsigned long long c0 = buf[wv][lane];
        unsigned long long c1 = buf[wv][64 + lane];
        unsigned long long c2 = buf[wv][128 + lane];
        unsigned long long c3 = buf[wv][192 + lane];
        for (int r = 0; r < KK; r++) {
            unsigned long long m01 = c0 < c1 ? c0 : c1;
            unsigned long long m23 = c2 < c3 ? c2 : c3;
            unsigned long long mm = m01 < m23 ? m01 : m23;
#pragma unroll
            for (int o = 32; o > 0; o >>= 1) {
                unsigned long long t2 = __shfl_xor(mm, o);
                mm = t2 < mm ? t2 : mm;
            }
            if (lane == r) kept = mm;
            c0 = (c0 == mm) ? ~0ull : c0;
            c1 = (c1 == mm) ? ~0ull : c1;
            c2 = (c2 == mm) ? ~0ull : c2;
            c3 = (c3 == mm) ? ~0ull : c3;
        }
    }

    bool act = (lane < KK);
    float gx = 0.0f, gy = 0.0f, gz = 0.0f;
    if (act) {
        unsigned nidx = (unsigned)kept;
        gx = pb[nidx * 3 + 0];
        gy = pb[nidx * 3 + 1];
        gz = pb[nidx * 3 + 2];
    }
    float dx = __fsub_rn(gx, qx);
    float dy = __fsub_rn(gy, qy);
    float dz = __fsub_rn(gz, qz);
    float mx = act ? dx : -3.402823466e38f;
    float my = act ? dy : -3.402823466e38f;
    float mz = act ? dz : -3.402823466e38f;
    float sx = act ? dx : 0.0f;
    float sy = act ? dy : 0.0f;
    float sz = act ? dz : 0.0f;
    double s1 = act ? ((double)dx + (double)dy + (double)dz) : 0.0;
    double s2 = act ? ((double)dx * dx + (double)dy * dy + (double)dz * dz) : 0.0;
#pragma unroll
    for (int o = 32; o > 0; o >>= 1) {
        mx = fmaxf(mx, __shfl_xor(mx, o));
        my = fmaxf(my, __shfl_xor(my, o));
        mz = fmaxf(mz, __shfl_xor(mz, o));
        sx += __shfl_xor(sx, o);
        sy += __shfl_xor(sy, o);
        sz += __shfl_xor(sz, o);
        s1 += __shfl_xor(s1, o);
        s2 += __shfl_xor(s2, o);
    }
    if (lane == 0) {
        float* a = A + ((size_t)b * SS + s) * 3;
        a[0] = __fadd_rn(mx, __fmul_rn(sx, 0.03125f));
        a[1] = __fadd_rn(my, __fmul_rn(sy, 0.03125f));
        a[2] = __fadd_rn(mz, __fmul_rn(sz, 0.03125f));
        qstats[2 * w + 0] = s1;
        qstats[2 * w + 1] = s2;
    }
}

// ---------------------------------------------------------------------------
// K2b: reduce per-query stats -> global stats[0..1]. One block.
// ---------------------------------------------------------------------------
__global__ __launch_bounds__(256) void reduce_stats_kernel(const double* __restrict__ qstats,
                                                           double* __restrict__ stats) {
    __shared__ double r1[4], r2[4];
    int t = threadIdx.x;
    double a = 0.0, bsum = 0.0;
    for (int i = t; i < BB * SS; i += 256) { a += qstats[2 * i]; bsum += qstats[2 * i + 1]; }
#pragma unroll
    for (int o = 32; o > 0; o >>= 1) { a += __shfl_xor(a, o); bsum += __shfl_xor(bsum, o); }
    int wv = t >> 6, ln = t & 63;
    if (ln == 0) { r1[wv] = a; r2[wv] = bsum; }
    __syncthreads();
    if (t == 0) {
        stats[0] = r1[0] + r1[1] + r1[2] + r1[3];
        stats[1] = r2[0] + r2[1] + r2[2] + r2[3];
    }
}

// ---------------------------------------------------------------------------
// K3: lc[b,c,s]: c<3 -> A/(std+1e-5); c>=3 -> 2*new_xyz. Accumulate BN1 sums.
// ---------------------------------------------------------------------------
__global__ __launch_bounds__(256) void lc_kernel(const float* __restrict__ new_xyz,
                                                 const float* __restrict__ A,
                                                 const double* __restrict__ stats,
                                                 float* __restrict__ lc,
                                                 double* __restrict__ bn1acc) {
    __shared__ double red[4];
    const int b = blockIdx.x / 6, c = blockIdx.x % 6;
    const int t = threadIdx.x;
    const double n = (double)BB * SS * KK * 3;
    double sd = stats[0], sq = stats[1];
    double var = (sq - sd * sd / n) / (n - 1.0);
    float stdv = (float)sqrt(var);
    float denom = __fadd_rn(stdv, 1e-5f);

    double s1 = 0.0, s2 = 0.0;
    for (int r = 0; r < 4; r++) {
        int s = r * 256 + t;
        float v;
        if (c < 3) {
            v = A[((size_t)b * SS + s) * 3 + c] / denom;
        } else {
            float ww = new_xyz[((size_t)b * SS + s) * 3 + (c - 3)];
            v = __fadd_rn(ww, ww);
        }
        lc[((size_t)b * 6 + c) * SS + s] = v;
        s1 += (double)v;
        s2 += (double)v * (double)v;
    }
#pragma unroll
    for (int off = 32; off > 0; off >>= 1) { s1 += __shfl_down(s1, off); s2 += __shfl_down(s2, off); }
    int wv = t >> 6, ln = t & 63;
    if (ln == 0) red[wv] = s1;
    __syncthreads();
    if (t == 0) atomicAdd(&bn1acc[c * 2 + 0], red[0] + red[1] + red[2] + red[3]);
    __syncthreads();
    if (ln == 0) red[wv] = s2;
    __syncthreads();
    if (t == 0) atomicAdd(&bn1acc[c * 2 + 1], red[0] + red[1] + red[2] + red[3]);
}

// ---------------------------------------------------------------------------
// K4a: per-batch: y = relu(BN1(lc)), then 6x6 safe cdist over S. 16 blocks.
// ---------------------------------------------------------------------------
__global__ __launch_bounds__(256) void cdist_kernel(const float* __restrict__ lc,
                                                    const double* __restrict__ bn1acc,
                                                    const float* __restrict__ params,
                                                    float* __restrict__ tf) {
    __shared__ float sy[6 * SS];
    const int b = blockIdx.x, t = threadIdx.x;
    float mean[6], sde[6], gg[6], bt[6];
    const double n = (double)BB * SS;
#pragma unroll
    for (int c = 0; c < 6; c++) {
        double m = bn1acc[c * 2 + 0] / n;
        double v = bn1acc[c * 2 + 1] / n - m * m;
        mean[c] = (float)m;
        sde[c] = sqrtf((float)v + 1e-5f);
        gg[c] = params[c];
        bt[c] = params[6 + c];
    }
    for (int r = 0; r < 24; r++) {
        int g = r * 256 + t;
        int c = g >> 10;
        float v = lc[(size_t)b * 6 * SS + g];
        float y = (v - mean[c]) / sde[c] * gg[c] + bt[c];
        sy[g] = fmaxf(y, 0.0f);
    }
    __syncthreads();
    if (t < 6) tf[b * 36 + t * 7] = 0.0f;

    const int w = t >> 6, lane = t & 63;
    const int PI[15] = {0,0,0,0,0,1,1,1,1,2,2,2,3,3,4};
    const int PJ[15] = {1,2,3,4,5,2,3,4,5,3,4,5,4,5,5};
    for (int r = 0; r < 4; r++) {
        int p = w + r * 4;
        if (p < 15) {
            int i = PI[p], j = PJ[p];
            float acc = 0.0f;
            for (int m2 = 0; m2 < 16; m2++) {
                int s = lane + m2 * 64;
                float d = sy[i * SS + s] - sy[j * SS + s];
                acc += d * d;
            }
#pragma unroll
            for (int off = 32; off > 0; off >>= 1) acc += __shfl_down(acc, off);
            if (lane == 0) {
                float v = acc > 0.0f ? sqrtf(acc) : 0.0f;
                const float FACTOR = 1.0f;
                tf[b * 36 + i * 6 + j] = (j == i + 1) ? v * FACTOR : v;
                tf[b * 36 + j * 6 + i] = v;
            }
        }
    }
}

// ---------------------------------------------------------------------------
// K4b: BN2 over batch per feature + relu -> out [16,36] (dtype per params[84]).
// ---------------------------------------------------------------------------
__global__ __launch_bounds__(64) void bn2_kernel(const float* __restrict__ tf,
                                                 const float* __restrict__ params,
                                                 void* __restrict__ out_raw) {
    int f = threadIdx.x;
    if (f >= 36) return;
    bool isbf = params[84] != 0.0f;
    float x[16]; float sum = 0.0f;
#pragma unroll
    for (int b = 0; b < 16; b++) { x[b] = tf[b * 36 + f]; sum += x[b]; }
    float mean = sum * 0.0625f;
    float vs = 0.0f;
#pragma unroll
    for (int b = 0; b < 16; b++) { float d = x[b] - mean; vs += d * d; }
    float var = vs * 0.0625f;
    float denom = sqrtf(var + 1e-5f);
    float g = params[12 + f], bb = params[48 + f];
#pragma unroll
    for (int b = 0; b < 16; b++) {
        float y = (x[b] - mean) / denom * g + bb;
        y = fmaxf(y, 0.0f);
        if (isbf) ((__hip_bfloat16*)out_raw)[b * 36 + f] = __float2bfloat16(y);
        else      ((float*)out_raw)[b * 36 + f] = y;
    }
}

// ---------------------------------------------------------------------------
// Workspace layout (bytes):
//   0        : xyzf     float[16*8192*3]   (1572864)  [written by fps now]
//   1572864  : new_xyz  float[16*1024*3]   (196608)
//   1769472  : A        float[16*1024*3]   (196608)
//   1966080  : lc       float[16*6*1024]   (393216)
//   2359296  : tfcw     float[16*36]       (2304)
//   2361600  : stats    double[14]
//   2361712  : params   float[85]
//   2362112  : qstats   double[16384*2]    (262144)
// ---------------------------------------------------------------------------
extern "C" void kernel_launch(void* const* d_in, const int* in_sizes, int n_in,
                              void* d_out, int out_size, void* d_ws, size_t ws_size,
                              hipStream_t stream) {
    const void* xyz_raw = d_in[0];
    const void* g1r = d_in[1]; const void* b1r = d_in[2];
    const void* g2r = d_in[3]; const void* b2r = d_in[4];
    {
        const void* six[2] = {nullptr, nullptr}; int n6 = 0;
        const void* t36[2] = {nullptr, nullptr}; int n36 = 0;
        const void* big = nullptr;
        for (int i = 0; i < n_in; i++) {
            if (in_sizes[i] == BB * NN * 3) big = d_in[i];
            else if (in_sizes[i] == 6  && n6  < 2) six[n6++]  = d_in[i];
            else if (in_sizes[i] == 36 && n36 < 2) t36[n36++] = d_in[i];
        }
        if (big && n6 == 2 && n36 == 2) {
            xyz_raw = big; g1r = six[0]; b1r = six[1]; g2r = t36[0]; b2r = t36[1];
        }
    }

    char* ws = (char*)d_ws;
    float* xyzf    = (float*)(ws + 0);
    float* new_xyz = (float*)(ws + 1572864);
    float* A       = (float*)(ws + 1769472);
    float* lc      = (float*)(ws + 1966080);
    float* tf      = (float*)(ws + 2359296);
    double* stats  = (double*)(ws + 2361600);
    double* bn1acc = stats + 2;
    float* params  = (float*)(ws + 2361712);
    double* qstats = (double*)(ws + 2362112);

    hipMemsetAsync(stats, 0, 14 * sizeof(double), stream);
    hipLaunchKernelGGL(convert_kernel, dim3(2), dim3(256), 0, stream,
                       xyz_raw, g1r, b1r, g2r, b2r, params, d_out);
    hipLaunchKernelGGL(fps_kernel,          dim3(16),   dim3(512), 0, stream,
                       xyz_raw, xyzf, new_xyz, params);
    hipLaunchKernelGGL(knn_kernel,          dim3(4096), dim3(256), 0, stream, xyzf, new_xyz, A, qstats);
    hipLaunchKernelGGL(reduce_stats_kernel, dim3(1),    dim3(256), 0, stream, qstats, stats);
    hipLaunchKernelGGL(lc_kernel,           dim3(96),   dim3(256), 0, stream, new_xyz, A, stats, lc, bn1acc);
    hipLaunchKernelGGL(cdist_kernel,        dim3(16),   dim3(256), 0, stream, lc, bn1acc, params, tf);
    hipLaunchKernelGGL(bn2_kernel,          dim3(1),    dim3(64),  0, stream, tf, params, d_out);

    (void)in_sizes; (void)n_in; (void)out_size; (void)ws_size;
}